// Round 5
// baseline (1854.866 us; speedup 1.0000x reference)
//
#include <hip/hip_runtime.h>
#include <hip/hip_bf16.h>
#include <math.h>

// Problem dims
#define BSZ 64
#define HGT 32
#define WID 32
#define HWN 1024
#define CCH 684
#define KP 704      // CCH padded to 22*32
#define VOC 128
#define NPP 512
#define QCH 256
#define EMB 256
#define HID 256
#define TAPP 128    // 121 taps padded
#define SAPAD 712   // 704 + 8 pad (16B-aligned rows, spreads banks)

typedef __attribute__((ext_vector_type(8))) short short8v;
typedef __attribute__((ext_vector_type(4))) float f32x4;

__device__ __forceinline__ float sigmoid_(float x) {
    return 1.0f / (1.0f + __expf(-x));
}
__device__ __forceinline__ float tanh_(float x) {
    x = fminf(fmaxf(x, -30.0f), 30.0f);
    float e = __expf(2.0f * x);
    return (e - 1.0f) / (e + 1.0f);
}
__device__ __forceinline__ unsigned short f2bf(float f) {
    unsigned int u = __float_as_uint(f);
    u = (u + 0x7FFFu + ((u >> 16) & 1u)) >> 16;
    return (unsigned short)u;
}

// ---------------------------------------------------------------------------
// K0: convert Ua_w (512x684 fp32, [p][c] k-contiguous) -> Ua_bf [512][704] bf16
__global__ __launch_bounds__(256) void k_prep_ua(const float* __restrict__ Ua_w,
                                                 unsigned short* __restrict__ Ua_bf) {
    int p = blockIdx.x;
    for (int c = threadIdx.x; c < KP; c += 256) {
        unsigned short v = 0;
        if (c < CCH) v = f2bf(Ua_w[p * CCH + c]);
        Ua_bf[p * KP + c] = v;
    }
}

// ---------------------------------------------------------------------------
// K1: fold conv into Uf. Block per p (512 blocks). Coalesced convQ_w reads.
// W2_bf[p][tap] = sum_q Uf_w[p,q]*convQ_w[q,tap]; covb[p] = Uf_b[p]+sum convQ_b*Uf
__global__ __launch_bounds__(256) void k_fold_w2(const float* __restrict__ Uf_w,
                                                 const float* __restrict__ Uf_b,
                                                 const float* __restrict__ convQ_w,
                                                 const float* __restrict__ convQ_b,
                                                 unsigned short* __restrict__ W2_bf,
                                                 float* __restrict__ covb) {
    int p = blockIdx.x;
    int t = threadIdx.x;
    __shared__ float s_uf[QCH];
    __shared__ float s_red[4];
    s_uf[t] = Uf_w[p * QCH + t];
    __syncthreads();
    if (t < TAPP) {
        float s = 0.f;
        if (t < 121) {
            for (int q = 0; q < QCH; q++) s += s_uf[q] * convQ_w[q * 121 + t];
        }
        W2_bf[p * TAPP + t] = (t < 121) ? f2bf(s) : (unsigned short)0;
    }
    float v = convQ_b[t] * s_uf[t];
#pragma unroll
    for (int m = 32; m >= 1; m >>= 1) v += __shfl_xor(v, m, 64);
    if ((t & 63) == 0) s_red[t >> 6] = v;
    __syncthreads();
    if (t == 0) covb[p] = Uf_b[p] + s_red[0] + s_red[1] + s_red[2] + s_red[3];
}

// ---------------------------------------------------------------------------
// K2: embedding gather + GRU1 + q0. Wave-per-row GEMV, coalesced weight reads.
__global__ __launch_bounds__(256) void k_embed_gru1(const int* __restrict__ x,
                                                    const float* __restrict__ hidden,
                                                    const float* __restrict__ emb,
                                                    const float* __restrict__ w_ih,
                                                    const float* __restrict__ w_hh,
                                                    const float* __restrict__ b_ih,
                                                    const float* __restrict__ b_hh,
                                                    const float* __restrict__ Wa_w,
                                                    const float* __restrict__ Wa_b,
                                                    const float* __restrict__ covb,
                                                    const float* __restrict__ Ua_b,
                                                    float* __restrict__ ws_emb,
                                                    float* __restrict__ ws_pred,
                                                    float* __restrict__ ws_q0) {
    int b = blockIdx.x, t = threadIdx.x;
    int wv = t >> 6, lane = t & 63;
    __shared__ float se[EMB], sh[HID], gi[768], gh[768], sp[HID];
    se[t] = emb[x[b] * EMB + t];
    sh[t] = hidden[b * HID + t];
    __syncthreads();

    // gi/gh: 768 rows each; wave wv handles rows [wv*192, +192)
    for (int i = 0; i < 192; i++) {
        int j = wv * 192 + i;
        const float* wi = w_ih + (size_t)j * EMB;
        const float* wh = w_hh + (size_t)j * HID;
        float s1 = wi[lane] * se[lane] + wi[lane + 64] * se[lane + 64] +
                   wi[lane + 128] * se[lane + 128] + wi[lane + 192] * se[lane + 192];
        float s2 = wh[lane] * sh[lane] + wh[lane + 64] * sh[lane + 64] +
                   wh[lane + 128] * sh[lane + 128] + wh[lane + 192] * sh[lane + 192];
#pragma unroll
        for (int m = 32; m >= 1; m >>= 1) {
            s1 += __shfl_xor(s1, m, 64);
            s2 += __shfl_xor(s2, m, 64);
        }
        if (lane == 0) { gi[j] = s1; gh[j] = s2; }
    }
    __syncthreads();

    float r = sigmoid_(gi[t] + b_ih[t] + gh[t] + b_hh[t]);
    float z = sigmoid_(gi[256 + t] + b_ih[256 + t] + gh[256 + t] + b_hh[256 + t]);
    float n = tanh_(gi[512 + t] + b_ih[512 + t] + r * (gh[512 + t] + b_hh[512 + t]));
    float pred = (1.0f - z) * n + z * sh[t];
    ws_emb[b * EMB + t] = se[t];
    ws_pred[b * HID + t] = pred;
    sp[t] = pred;
    __syncthreads();

    // q0: 512 rows; wave handles [wv*128, +128)
    for (int i = 0; i < 128; i++) {
        int j = wv * 128 + i;
        const float* wq = Wa_w + (size_t)j * HID;
        float q = wq[lane] * sp[lane] + wq[lane + 64] * sp[lane + 64] +
                  wq[lane + 128] * sp[lane + 128] + wq[lane + 192] * sp[lane + 192];
#pragma unroll
        for (int m = 32; m >= 1; m >>= 1) q += __shfl_xor(q, m, 64);
        if (lane == 0) ws_q0[b * NPP + j] = q + Wa_b[j] + covb[j] + Ua_b[j];
    }
}

// ---------------------------------------------------------------------------
// K3: MFMA fused score kernel v3. Block = (rb, b): 64 hw x 512 p, 8 waves.
// Whole A-tile (64x704 bf16) staged in LDS once; main K-loop is barrier-free:
// A-frags from LDS, B-frags direct from L2. Each wave: 64 hw x 64 p, acc[4][4].
__global__ __launch_bounds__(512, 2) void k_score(const float* __restrict__ feature,
                                                  const float* __restrict__ alpha,
                                                  const unsigned short* __restrict__ Ua_bf,
                                                  const unsigned short* __restrict__ W2_bf,
                                                  const float* __restrict__ ws_q0,
                                                  const float* __restrict__ Va_w,
                                                  const float* __restrict__ Va_b,
                                                  float* __restrict__ ws_et) {
    int rb = blockIdx.x;   // hw-chunk: [rb*64, rb*64+64)
    int b = blockIdx.y;
    int tid = threadIdx.x;       // 0..511
    int wv = tid >> 6;           // 0..7
    int lane = tid & 63;
    int li = lane & 15;
    int k08 = (lane >> 4) * 8;
    int pbase = wv * 64;

    __shared__ unsigned short s_a[64 * SAPAD];   // 91136 B: A-tile [hw][k]
    __shared__ unsigned short s_a2[64 * 136];    // 17408 B: stencil A [hw][tap]
    __shared__ float s_et[64];

    // ---- stage A: feature fp32 [c][hw-slice] -> bf16 s_a[hw][c] ----
    const float* fbase = feature + (size_t)b * CCH * HWN + rb * 64;
    for (int idx = tid; idx < 64 * CCH; idx += 512) {
        int c = idx >> 6, hw = idx & 63;
        s_a[hw * SAPAD + c] = f2bf(fbase[(size_t)c * HWN + hw]);
    }
    for (int idx = tid; idx < 64 * (SAPAD - CCH); idx += 512) {
        int hw = idx / (SAPAD - CCH), c = CCH + idx % (SAPAD - CCH);
        s_a[hw * SAPAD + c] = 0;
    }
    // ---- stage stencil operand (beta halo, bf16) ----
    for (int idx = tid; idx < 64 * 128; idx += 512) {
        int hwl = idx >> 7, tap = idx & 127;
        unsigned short v = 0;
        if (tap < 121) {
            int ky = tap / 11, kx = tap - ky * 11;
            int hwg = rb * 64 + hwl;
            int y = (hwg >> 5) + ky - 5;
            int xx = (hwg & 31) + kx - 5;
            if (y >= 0 && y < HGT && xx >= 0 && xx < WID)
                v = f2bf(alpha[b * HWN + y * WID + xx]);
        }
        s_a2[hwl * 136 + tap] = v;
    }
    if (tid < 64) s_et[tid] = 0.f;
    __syncthreads();

    f32x4 acc[4][4];
#pragma unroll
    for (int mt = 0; mt < 4; mt++)
#pragma unroll
        for (int nt = 0; nt < 4; nt++) acc[mt][nt] = (f32x4){0.f, 0.f, 0.f, 0.f};

    // ---- key_t: 22 barrier-free K-steps of 32 ----
    for (int s = 0; s < 22; s++) {
        int c0 = s * 32;
        short8v af[4];
#pragma unroll
        for (int mt = 0; mt < 4; mt++)
            af[mt] = *reinterpret_cast<const short8v*>(&s_a[(mt * 16 + li) * SAPAD + c0 + k08]);
#pragma unroll
        for (int nt = 0; nt < 4; nt++) {
            short8v bv = *reinterpret_cast<const short8v*>(
                Ua_bf + (size_t)(pbase + nt * 16 + li) * KP + c0 + k08);
#pragma unroll
            for (int mt = 0; mt < 4; mt++)
                acc[mt][nt] = __builtin_amdgcn_mfma_f32_16x16x32_bf16(af[mt], bv, acc[mt][nt], 0, 0, 0);
        }
    }

    // ---- cover stencil: 4 K-steps of 32 taps ----
#pragma unroll
    for (int s = 0; s < 4; s++) {
        int t0 = s * 32;
        short8v af[4];
#pragma unroll
        for (int mt = 0; mt < 4; mt++)
            af[mt] = *reinterpret_cast<const short8v*>(&s_a2[(mt * 16 + li) * 136 + t0 + k08]);
#pragma unroll
        for (int nt = 0; nt < 4; nt++) {
            short8v bv = *reinterpret_cast<const short8v*>(
                W2_bf + (size_t)(pbase + nt * 16 + li) * TAPP + t0 + k08);
#pragma unroll
            for (int mt = 0; mt < 4; mt++)
                acc[mt][nt] = __builtin_amdgcn_mfma_f32_16x16x32_bf16(af[mt], bv, acc[mt][nt], 0, 0, 0);
        }
    }

    // ---- epilogue: +q0, tanh, *Va, reduce over p ----
    float part[4][4];
#pragma unroll
    for (int mt = 0; mt < 4; mt++)
#pragma unroll
        for (int r = 0; r < 4; r++) part[mt][r] = 0.f;

#pragma unroll
    for (int nt = 0; nt < 4; nt++) {
        int p = pbase + nt * 16 + li;
        float q0 = ws_q0[b * NPP + p];
        float va = Va_w[p];
#pragma unroll
        for (int mt = 0; mt < 4; mt++)
#pragma unroll
            for (int r = 0; r < 4; r++)
                part[mt][r] += va * tanh_(acc[mt][nt][r] + q0);
    }
#pragma unroll
    for (int mask = 1; mask <= 8; mask <<= 1)
#pragma unroll
        for (int mt = 0; mt < 4; mt++)
#pragma unroll
            for (int r = 0; r < 4; r++)
                part[mt][r] += __shfl_xor(part[mt][r], mask, 64);

    if (li == 0) {
        int rb4 = (lane >> 4) * 4;
#pragma unroll
        for (int mt = 0; mt < 4; mt++)
#pragma unroll
            for (int r = 0; r < 4; r++)
                atomicAdd(&s_et[mt * 16 + rb4 + r], part[mt][r]);
    }
    __syncthreads();
    if (tid < 64) ws_et[b * HWN + rb * 64 + tid] = s_et[tid] + Va_b[0];
}

// ---------------------------------------------------------------------------
// K4: softmax over 1024 positions per batch (exact ref semantics: exp, no shift)
__global__ __launch_bounds__(256) void k_softmax(const float* __restrict__ ws_et,
                                                 float* __restrict__ alpha_out) {
    int b = blockIdx.x, t = threadIdx.x;
    __shared__ float red[4];
    float e[4];
    float s = 0.f;
#pragma unroll
    for (int i = 0; i < 4; i++) {
        e[i] = expf(ws_et[b * HWN + t + i * 256]);
        s += e[i];
    }
#pragma unroll
    for (int off = 32; off >= 1; off >>= 1) s += __shfl_xor(s, off, 64);
    int wid = t >> 6;
    if ((t & 63) == 0) red[wid] = s;
    __syncthreads();
    float tot = red[0] + red[1] + red[2] + red[3] + 1e-8f;
    float inv = 1.0f / tot;
#pragma unroll
    for (int i = 0; i < 4; i++) alpha_out[b * HWN + t + i * 256] = e[i] * inv;
}

// ---------------------------------------------------------------------------
// K5: context[b,c] = sum_hw feature[b,c,hw] * alpha[b,hw]   (1 wave per (b,c))
__global__ __launch_bounds__(256) void k_context(const float* __restrict__ feature,
                                                 const float* __restrict__ alpha_out,
                                                 float* __restrict__ ws_ctx) {
    int b = blockIdx.x;
    int c = blockIdx.y * 4 + (threadIdx.x >> 6);
    int lane = threadIdx.x & 63;
    const float* f = feature + ((size_t)b * CCH + c) * HWN;
    const float* a = alpha_out + b * HWN;
    float s = 0.f;
    for (int k = lane; k < HWN; k += 64) s += f[k] * a[k];
#pragma unroll
    for (int off = 32; off >= 1; off >>= 1) s += __shfl_xor(s, off, 64);
    if (lane == 0) ws_ctx[b * CCH + c] = s;
}

// ---------------------------------------------------------------------------
// K6: GRU2 + output head. Wave-per-row GEMV, coalesced weight reads.
__global__ __launch_bounds__(256) void k_final(const float* __restrict__ ws_ctx,
                                               const float* __restrict__ ws_pred,
                                               const float* __restrict__ ws_emb,
                                               const float* __restrict__ w_ih2,
                                               const float* __restrict__ w_hh2,
                                               const float* __restrict__ b_ih2,
                                               const float* __restrict__ b_hh2,
                                               const float* __restrict__ Ws_w,
                                               const float* __restrict__ Ws_b,
                                               const float* __restrict__ Wc_w,
                                               const float* __restrict__ Wc_b,
                                               const float* __restrict__ Wo_w,
                                               const float* __restrict__ Wo_b,
                                               float* __restrict__ out_logits,
                                               float* __restrict__ out_h2) {
    int b = blockIdx.x, t = threadIdx.x;
    int wv = t >> 6, lane = t & 63;
    __shared__ float sc[CCH], sp[HID], semb[EMB], gi2[768], gh2[768], sh2[HID], so[EMB], som[VOC];
    for (int i = t; i < CCH; i += 256) sc[i] = ws_ctx[b * CCH + i];
    sp[t] = ws_pred[b * HID + t];
    semb[t] = ws_emb[b * EMB + t];
    __syncthreads();

    // gi2 (K=684), gh2 (K=256): 768 rows each; wave handles [wv*192, +192)
    for (int i = 0; i < 192; i++) {
        int j = wv * 192 + i;
        const float* wi = w_ih2 + (size_t)j * CCH;
        const float* wh = w_hh2 + (size_t)j * HID;
        float s1 = 0.f;
        for (int kk = lane; kk < CCH; kk += 64) s1 += wi[kk] * sc[kk];
        float s2 = wh[lane] * sp[lane] + wh[lane + 64] * sp[lane + 64] +
                   wh[lane + 128] * sp[lane + 128] + wh[lane + 192] * sp[lane + 192];
#pragma unroll
        for (int m = 32; m >= 1; m >>= 1) {
            s1 += __shfl_xor(s1, m, 64);
            s2 += __shfl_xor(s2, m, 64);
        }
        if (lane == 0) { gi2[j] = s1; gh2[j] = s2; }
    }
    __syncthreads();

    float rg = sigmoid_(gi2[t] + b_ih2[t] + gh2[t] + b_hh2[t]);
    float zg = sigmoid_(gi2[256 + t] + b_ih2[256 + t] + gh2[256 + t] + b_hh2[256 + t]);
    float ng = tanh_(gi2[512 + t] + b_ih2[512 + t] + rg * (gh2[512 + t] + b_hh2[512 + t]));
    float h2 = (1.0f - zg) * ng + zg * sp[t];
    out_h2[b * HID + t] = h2;
    sh2[t] = h2;
    __syncthreads();

    // o = emb + h2@Ws.T + Ws_b + ctx@Wc.T + Wc_b : 256 rows; wave [wv*64,+64)
    for (int i = 0; i < 64; i++) {
        int j = wv * 64 + i;
        const float* wsr = Ws_w + (size_t)j * HID;
        const float* wcr = Wc_w + (size_t)j * CCH;
        float s = wsr[lane] * sh2[lane] + wsr[lane + 64] * sh2[lane + 64] +
                  wsr[lane + 128] * sh2[lane + 128] + wsr[lane + 192] * sh2[lane + 192];
        for (int kk = lane; kk < CCH; kk += 64) s += wcr[kk] * sc[kk];
#pragma unroll
        for (int m = 32; m >= 1; m >>= 1) s += __shfl_xor(s, m, 64);
        if (lane == 0) so[j] = s + semb[j] + Ws_b[j] + Wc_b[j];
    }
    __syncthreads();
    if (t < VOC) som[t] = fmaxf(so[2 * t], so[2 * t + 1]);
    __syncthreads();

    // logits: 128 rows K=128; wave handles [wv*32,+32)
    for (int i = 0; i < 32; i++) {
        int j = wv * 32 + i;
        const float* wo = Wo_w + (size_t)j * VOC;
        float s = wo[lane] * som[lane] + wo[lane + 64] * som[lane + 64];
#pragma unroll
        for (int m = 32; m >= 1; m >>= 1) s += __shfl_xor(s, m, 64);
        if (lane == 0) out_logits[b * VOC + j] = s + Wo_b[j];
    }
}

// ---------------------------------------------------------------------------
extern "C" void kernel_launch(void* const* d_in, const int* in_sizes, int n_in,
                              void* d_out, int out_size, void* d_ws, size_t ws_size,
                              hipStream_t stream) {
    const int* x = (const int*)d_in[0];
    const float* hidden = (const float*)d_in[1];
    const float* feature = (const float*)d_in[2];
    const float* alpha = (const float*)d_in[3];
    const float* emb = (const float*)d_in[4];
    const float* gru1_wih = (const float*)d_in[5];
    const float* gru1_whh = (const float*)d_in[6];
    const float* gru1_bih = (const float*)d_in[7];
    const float* gru1_bhh = (const float*)d_in[8];
    const float* gru2_wih = (const float*)d_in[9];
    const float* gru2_whh = (const float*)d_in[10];
    const float* gru2_bih = (const float*)d_in[11];
    const float* gru2_bhh = (const float*)d_in[12];
    const float* convQ_w = (const float*)d_in[13];
    const float* convQ_b = (const float*)d_in[14];
    const float* Wa_w = (const float*)d_in[15];
    const float* Wa_b = (const float*)d_in[16];
    const float* Ua_w = (const float*)d_in[17];
    const float* Ua_b = (const float*)d_in[18];
    const float* Uf_w = (const float*)d_in[19];
    const float* Uf_b = (const float*)d_in[20];
    const float* Va_w = (const float*)d_in[21];
    const float* Va_b = (const float*)d_in[22];
    const float* Ws_w = (const float*)d_in[23];
    const float* Ws_b = (const float*)d_in[24];
    const float* Wc_w = (const float*)d_in[25];
    const float* Wc_b = (const float*)d_in[26];
    const float* Wo_w = (const float*)d_in[27];
    const float* Wo_b = (const float*)d_in[28];

    float* out = (float*)d_out;
    float* out_logits = out;                         // 64*128
    float* out_h2 = out + BSZ * VOC;                 // 64*256
    float* out_alpha = out + BSZ * VOC + BSZ * HID;  // 64*1024

    float* ws = (float*)d_ws;
    float* ws_emb = ws;                          // 16384 floats
    float* ws_pred = ws + 16384;                 // 16384
    float* ws_q0 = ws + 32768;                   // 32768
    float* ws_et = ws + 65536;                   // 65536
    float* ws_ctx = ws + 131072;                 // 43776 (pad to 44032)
    float* ws_covb = ws + 175104;                // 512
    unsigned short* Ua_bf = (unsigned short*)(ws + 175616);  // 512*704 u16
    unsigned short* W2_bf = (unsigned short*)(ws + 355840);  // 512*128 u16
    // total ~1.55 MB

    k_prep_ua<<<NPP, 256, 0, stream>>>(Ua_w, Ua_bf);
    k_fold_w2<<<NPP, 256, 0, stream>>>(Uf_w, Uf_b, convQ_w, convQ_b, W2_bf, ws_covb);
    k_embed_gru1<<<BSZ, 256, 0, stream>>>(x, hidden, emb, gru1_wih, gru1_whh,
                                          gru1_bih, gru1_bhh, Wa_w, Wa_b,
                                          ws_covb, Ua_b,
                                          ws_emb, ws_pred, ws_q0);
    k_score<<<dim3(16, BSZ), 512, 0, stream>>>(feature, alpha, Ua_bf, W2_bf,
                                               ws_q0, Va_w, Va_b, ws_et);
    k_softmax<<<BSZ, 256, 0, stream>>>(ws_et, out_alpha);
    k_context<<<dim3(BSZ, 171), 256, 0, stream>>>(feature, out_alpha, ws_ctx);
    k_final<<<BSZ, 256, 0, stream>>>(ws_ctx, ws_pred, ws_emb, gru2_wih, gru2_whh,
                                     gru2_bih, gru2_bhh, Ws_w, Ws_b, Wc_w, Wc_b,
                                     Wo_w, Wo_b, out_logits, out_h2);
}